// Round 11
// baseline (114.463 us; speedup 1.0000x reference)
//
#include <hip/hip_runtime.h>
#include <hip/hip_bf16.h>
#include <math.h>

// FlexMaxPool: segment_max(features[in_idx], out_idx, num_segments=N_POINTS)
// R27 = R21 binsort + SPLIT feature table (two contiguous 3.2MB halves) +
// two-kernel phase-aligned gather (kernel boundary = the only machine-wide
// barrier this harness allows).
//  - R26 post-mortem: hipLaunchCooperativeKernel silently rejected under graph
//    capture (output stayed zero). Coop sync unavailable.
//  - L2-residency arithmetic has never been falsified on its own terms; only
//    the ALIGNMENT failed (R19 block sync, R24 bid%8, R26 coop). Kernel-launch
//    boundaries are stream-ordered machine-wide barriers that DO work.
//  - Pool A: R21 prologue, dump sortedg/startg, gather half A from f16a
//    (3.2MB contiguous -> resident in every XCD's 4MB L2 by construction).
//  - Pool B: reload sortedg/startg (coalesced), gather half B from f16b.
//  - Gather: 4 lanes x uint4 per 64B half-row, 8-lane group = 2 edges/iter,
//    4-deep unroll, 16 pk_max chains, shfl_xor(4) combine. Same 1KB/instr as
//    R21 (R24's uint2 width mistake avoided).
//  - FALSIFIABLE: pool FETCH must drop ~117MB -> ~65MB, else model is dead.
//
// ws: f16a 3.2MB | f16b 3.2MB | chunkd 6.4MB | pfxg 1MB | sortedg 8MB | startg 203KB

#define N_POINTS 50000
#define N_EDGES  1600000
#define CHANNELS 64
#define BIN_SHIFT 6
#define BIN_PTS   64
#define NBINS     782              // ceil(50000/64)
#define NBINS_PAD 1024
#define CAPL      2560             // per-bin list capacity (mean 2046, +11 sigma)
#define QCAP      2560
#define P1_GRID   256
#define P1_BLK    1024
#define ECHUNK    (N_EDGES / P1_GRID)               // 6250, exact
#define ECHUNK_PAD 6256                             // next multiple of 4
#define CVT_TOTAL (N_POINTS * CHANNELS / 4)         // 800000 float4
#define CVT_PER   ((CVT_TOTAL + P1_GRID - 1) / P1_GRID)   // 3125

__device__ __forceinline__ unsigned int encode_bf16(float x) {
    unsigned int u = __float_as_uint(x);
    unsigned int r = ((u >> 16) & 1u) + 0x7FFFu;
    unsigned int h = (u + r) >> 16;
    return (h & 0x8000u) ? (h ^ 0xFFFFu) : (h | 0x8000u);
}

__device__ __forceinline__ float decode_u16(unsigned int v) {
    if (v == 0u) return -INFINITY;
    unsigned int h = (v & 0x8000u) ? (v ^ 0x8000u) : (v ^ 0xFFFFu);
    return __uint_as_float(h << 16);
}

__device__ __forceinline__ unsigned int pk_max_u16(unsigned int a, unsigned int b) {
    unsigned int d;
    asm("v_pk_max_u16 %0, %1, %2" : "=v"(d) : "v"(a), "v"(b));
    return d;
}

// Counting sort of a 6250-edge chunk by 64-pt bin (dst>>6) into LDS, then a
// fully-coalesced contiguous dump (uint4) + per-chunk prefix table. Feature
// conversion now writes TWO contiguous half-tables (ch 0-31 -> f16a,
// ch 32-63 -> f16b).   [R21 + split-table cvt]
__global__ __launch_bounds__(P1_BLK) void binsort_cvt_kernel(
    const int2*   __restrict__ idx,
    const float4* __restrict__ feat4,
    uint2*        __restrict__ f16a,
    uint2*        __restrict__ f16b,
    unsigned int* __restrict__ chunkd,
    unsigned int* __restrict__ pfxg)
{
    __shared__ unsigned int hist[NBINS_PAD];
    __shared__ unsigned int pfx[NBINS_PAD];
    __shared__ __align__(16) unsigned int staging[ECHUNK_PAD];   // 25 KB
    __shared__ unsigned int wsum[16];

    int tid  = threadIdx.x;
    int lane = tid & 63, w = tid >> 6;

    // ---- feature-convert slice (split-table) ----
    {
        int cb = blockIdx.x * CVT_PER;
        #pragma unroll
        for (int k = 0; k < 4; ++k) {
            int i = cb + k * P1_BLK + tid;
            if (i < cb + CVT_PER && i < CVT_TOTAL) {
                float4 v = feat4[i];
                uint2 r;
                r.x = encode_bf16(v.x) | (encode_bf16(v.y) << 16);
                r.y = encode_bf16(v.z) | (encode_bf16(v.w) << 16);
                int p = i >> 4, q = i & 15;           // point, float4-within-row
                if (q < 8) f16a[p * 8 + q] = r;
                else       f16b[p * 8 + (q - 8)] = r;
            }
        }
    }

    // ---- counting sort ----
    int base = blockIdx.x * ECHUNK;

    hist[tid] = 0u;
    __syncthreads();

    int2 e[7]; unsigned int slot[7];
    #pragma unroll
    for (int j = 0; j < 7; ++j) {
        int i = j * P1_BLK + tid;
        if (i < ECHUNK) {
            e[j] = idx[base + i];
            slot[j] = atomicAdd(&hist[(unsigned)e[j].x >> BIN_SHIFT], 1u);
        }
    }
    __syncthreads();

    // Exclusive prefix over 1024 bins, all 16 waves participating.
    {
        unsigned int a = hist[tid];
        unsigned int inc = a;
        #pragma unroll
        for (int d = 1; d < 64; d <<= 1) {
            unsigned int v = __shfl_up(inc, d, 64);
            if (lane >= d) inc += v;
        }
        if (lane == 63) wsum[w] = inc;
        __syncthreads();
        unsigned int woff = 0;
        #pragma unroll
        for (int k = 0; k < 16; ++k) if (k < w) woff += wsum[k];
        pfx[tid] = woff + inc - a;
    }
    __syncthreads();

    #pragma unroll
    for (int j = 0; j < 7; ++j) {
        int i = j * P1_BLK + tid;
        if (i < ECHUNK) {
            unsigned int dst = (unsigned)e[j].x, src = (unsigned)e[j].y;
            unsigned int bin = dst >> BIN_SHIFT;
            staging[pfx[bin] + slot[j]] =
                (bin << 22) | ((dst & (BIN_PTS - 1)) << 16) | src;
        }
    }
    if (tid < ECHUNK_PAD - ECHUNK) staging[ECHUNK + tid] = 0u;   // dump pad
    __syncthreads();

    // Fully-coalesced dump: 1564 uint4 + 1024-entry prefix table.
    {
        const uint4* st4 = (const uint4*)staging;
        uint4* cd4 = (uint4*)(chunkd + (size_t)blockIdx.x * ECHUNK_PAD);
        #pragma unroll
        for (int k = 0; k < 2; ++k) {
            int i = k * P1_BLK + tid;
            if (i < ECHUNK_PAD / 4) cd4[i] = st4[i];
        }
        pfxg[blockIdx.x * NBINS_PAD + tid] = pfx[tid];
    }
}

// Shared gather body: 8-lane group per point, 2 edges/iteration
// (lanes 0-3 = edge i, lanes 4-7 = edge i+1), uint4 per lane (8 channels of
// the 64B half-row), 16 pk_max chains, shfl_xor(4) combine, lanes el==0 write.
__device__ __forceinline__ void gather_half(
    const uint4* __restrict__ fh4,             // half-table as uint4 rows of 4
    const unsigned int* __restrict__ sorted,   // LDS, pre-scaled src*4
    const unsigned int* __restrict__ start,    // LDS, 65 entries
    float4* __restrict__ out4, int bin, int half, int tid)
{
    int g = tid >> 3, ln = tid & 7;
    int el = ln >> 2, l4 = ln & 3;
    unsigned int s0 = start[g], s1 = start[g + 1];
    if (s1 > QCAP) s1 = QCAP;

    unsigned int A0=0,A1=0,A2=0,A3=0, B0=0,B1=0,B2=0,B3=0;
    unsigned int C0=0,C1=0,C2=0,C3=0, D0=0,D1=0,D2=0,D3=0;
    unsigned int i = s0 + (unsigned)el;
    for (; i + 6 < s1; i += 8) {
        unsigned int r0 = sorted[i+0], r1 = sorted[i+2];
        unsigned int r2 = sorted[i+4], r3 = sorted[i+6];
        uint4 u0 = fh4[r0 + l4];
        uint4 u1 = fh4[r1 + l4];
        uint4 u2 = fh4[r2 + l4];
        uint4 u3 = fh4[r3 + l4];
        A0 = pk_max_u16(A0, u0.x); A1 = pk_max_u16(A1, u0.y);
        A2 = pk_max_u16(A2, u0.z); A3 = pk_max_u16(A3, u0.w);
        B0 = pk_max_u16(B0, u1.x); B1 = pk_max_u16(B1, u1.y);
        B2 = pk_max_u16(B2, u1.z); B3 = pk_max_u16(B3, u1.w);
        C0 = pk_max_u16(C0, u2.x); C1 = pk_max_u16(C1, u2.y);
        C2 = pk_max_u16(C2, u2.z); C3 = pk_max_u16(C3, u2.w);
        D0 = pk_max_u16(D0, u3.x); D1 = pk_max_u16(D1, u3.y);
        D2 = pk_max_u16(D2, u3.z); D3 = pk_max_u16(D3, u3.w);
    }
    for (; i < s1; i += 2) {
        uint4 u = fh4[sorted[i] + l4];
        A0 = pk_max_u16(A0, u.x); A1 = pk_max_u16(A1, u.y);
        A2 = pk_max_u16(A2, u.z); A3 = pk_max_u16(A3, u.w);
    }
    A0 = pk_max_u16(pk_max_u16(A0, B0), pk_max_u16(C0, D0));
    A1 = pk_max_u16(pk_max_u16(A1, B1), pk_max_u16(C1, D1));
    A2 = pk_max_u16(pk_max_u16(A2, B2), pk_max_u16(C2, D2));
    A3 = pk_max_u16(pk_max_u16(A3, B3), pk_max_u16(C3, D3));

    // Combine the two 4-lane subgroups (lane xor 4).
    A0 = pk_max_u16(A0, (unsigned int)__shfl_xor((int)A0, 4));
    A1 = pk_max_u16(A1, (unsigned int)__shfl_xor((int)A1, 4));
    A2 = pk_max_u16(A2, (unsigned int)__shfl_xor((int)A2, 4));
    A3 = pk_max_u16(A3, (unsigned int)__shfl_xor((int)A3, 4));

    int gp = bin * BIN_PTS + g;
    if (gp < N_POINTS && el == 0) {
        float4 o0, o1;
        o0.x = decode_u16(A0 & 0xFFFFu); o0.y = decode_u16(A0 >> 16);
        o0.z = decode_u16(A1 & 0xFFFFu); o0.w = decode_u16(A1 >> 16);
        o1.x = decode_u16(A2 & 0xFFFFu); o1.y = decode_u16(A2 >> 16);
        o1.z = decode_u16(A3 & 0xFFFFu); o1.w = decode_u16(A3 >> 16);
        out4[(size_t)gp * 16 + half * 8 + l4 * 2 + 0] = o0;
        out4[(size_t)gp * 16 + half * 8 + l4 * 2 + 1] = o1;
    }
}

// Pool A: R21 prologue (concat + LDS sort), dump sortedg/startg, gather half 0.
// Machine-wide feature working set during gather = f16a (3.2MB, L2-resident).
__global__ __launch_bounds__(512) void pool_a_kernel(
    const unsigned int* __restrict__ f16a,
    const unsigned int* __restrict__ chunkd,
    const unsigned int* __restrict__ pfxg,
    unsigned int* __restrict__ sortedg,
    unsigned int* __restrict__ startg,
    float4* __restrict__ out4)
{
    __shared__ unsigned int list[CAPL];        // 10 KB
    __shared__ unsigned int sorted[QCAP];      // 10 KB
    __shared__ unsigned int choff[P1_GRID];
    __shared__ unsigned int hist[64];
    __shared__ unsigned int start[65];
    __shared__ unsigned int cur[64];
    __shared__ unsigned int wsum4[4];
    __shared__ unsigned int Tsh;

    int tid = threadIdx.x;
    int bin = blockIdx.x;
    int lane = tid & 63, w = tid >> 6;

    if (tid < 64) hist[tid] = 0u;

    // Per-chunk segment bounds + exclusive scan of counts (4 waves).
    unsigned int cntc = 0, inc = 0;
    if (tid < P1_GRID) {
        unsigned int s = pfxg[tid * NBINS_PAD + bin];
        unsigned int e = pfxg[tid * NBINS_PAD + bin + 1];
        cntc = e - s;
        inc = cntc;
        #pragma unroll
        for (int d = 1; d < 64; d <<= 1) {
            unsigned int v = __shfl_up(inc, d, 64);
            if (lane >= d) inc += v;
        }
        if (lane == 63) wsum4[w] = inc;
    }
    __syncthreads();
    if (tid < P1_GRID) {
        unsigned int woff = 0;
        #pragma unroll
        for (int k = 0; k < 4; ++k) if (k < w) woff += wsum4[k];
        unsigned int off = woff + inc - cntc;
        choff[tid] = off;
        if (tid == P1_GRID - 1) Tsh = off + cntc;
    }
    __syncthreads();

    unsigned int T = Tsh; if (T > CAPL) T = CAPL;

    // Copy segments: 2 threads per chunk (interleaved halves).
    {
        int c = tid >> 1, h = tid & 1;
        unsigned int s = pfxg[c * NBINS_PAD + bin];
        unsigned int e = pfxg[c * NBINS_PAD + bin + 1];
        unsigned int n = e - s;
        unsigned int off = choff[c];
        unsigned int g0 = (unsigned)c * ECHUNK_PAD + s;
        for (unsigned int j = h; j < n; j += 2) {
            unsigned int v = chunkd[g0 + j];
            if (off + j < CAPL) list[off + j] = v;
        }
    }
    __syncthreads();

    // Histogram the bin's entries over 64 points.
    for (unsigned int t = tid; t < T; t += 512)
        atomicAdd(&hist[(list[t] >> 16) & 63], 1u);
    __syncthreads();

    // Scan 64 sub-bins with wave 0.
    if (tid < 64) {
        unsigned int h = hist[tid], inc2 = h;
        #pragma unroll
        for (int d = 1; d < 64; d <<= 1) {
            unsigned int v = __shfl_up(inc2, d, 64);
            if (tid >= d) inc2 += v;
        }
        start[tid] = inc2 - h; cur[tid] = inc2 - h;
        if (tid == 63) start[64] = inc2;
    }
    __syncthreads();

    for (unsigned int t = tid; t < T; t += 512) {
        unsigned int v = list[t];
        unsigned int slot = atomicAdd(&cur[(v >> 16) & 63], 1u);
        if (slot < QCAP) sorted[slot] = (v & 0xFFFFu) << 2;   // src * 4 uint4-rows
    }
    __syncthreads();

    // Dump sorted list + start offsets for kernel B (coalesced).
    for (unsigned int t = tid; t < T; t += 512)
        sortedg[(size_t)bin * QCAP + t] = sorted[t];
    if (tid < 65) startg[bin * 65 + tid] = start[tid];

    gather_half((const uint4*)f16a, sorted, start, out4, bin, 0, tid);
}

// Pool B: reload sortedg/startg, gather half 1 from f16b (3.2MB, L2-resident).
__global__ __launch_bounds__(512) void pool_b_kernel(
    const unsigned int* __restrict__ f16b,
    const unsigned int* __restrict__ sortedg,
    const unsigned int* __restrict__ startg,
    float4* __restrict__ out4)
{
    __shared__ unsigned int sorted[QCAP];      // 10 KB
    __shared__ unsigned int start[65];

    int tid = threadIdx.x;
    int bin = blockIdx.x;

    if (tid < 65) start[tid] = startg[bin * 65 + tid];
    __syncthreads();
    unsigned int T = start[64]; if (T > QCAP) T = QCAP;
    for (unsigned int t = tid; t < T; t += 512)
        sorted[t] = sortedg[(size_t)bin * QCAP + t];
    __syncthreads();

    gather_half((const uint4*)f16b, sorted, start, out4, bin, 1, tid);
}

extern "C" void kernel_launch(void* const* d_in, const int* in_sizes, int n_in,
                              void* d_out, int out_size, void* d_ws, size_t ws_size,
                              hipStream_t stream) {
    const float4* feat4 = (const float4*)d_in[0];
    const int2*   idx   = (const int2*)d_in[1];

    size_t off_f16a   = 0;
    size_t off_f16b   = (size_t)N_POINTS * CHANNELS;                     // 3.2 MB
    size_t off_chunk  = off_f16b + (size_t)N_POINTS * CHANNELS;          // +3.2 MB
    size_t off_pfxg   = off_chunk + (size_t)P1_GRID * ECHUNK_PAD * 4;    // +6.4 MB
    size_t off_sorted = off_pfxg + (size_t)P1_GRID * NBINS_PAD * 4;      // +1 MB
    size_t off_startg = off_sorted + (size_t)NBINS * QCAP * 4;           // +8 MB
    uint2*        f16a    = (uint2*)((char*)d_ws + off_f16a);
    uint2*        f16b    = (uint2*)((char*)d_ws + off_f16b);
    unsigned int* chunkd  = (unsigned int*)((char*)d_ws + off_chunk);
    unsigned int* pfxg    = (unsigned int*)((char*)d_ws + off_pfxg);
    unsigned int* sortedg = (unsigned int*)((char*)d_ws + off_sorted);
    unsigned int* startg  = (unsigned int*)((char*)d_ws + off_startg);

    binsort_cvt_kernel<<<P1_GRID, P1_BLK, 0, stream>>>(idx, feat4, f16a, f16b,
                                                       chunkd, pfxg);
    pool_a_kernel<<<NBINS, 512, 0, stream>>>((const unsigned int*)f16a, chunkd,
                                             pfxg, sortedg, startg, (float4*)d_out);
    pool_b_kernel<<<NBINS, 512, 0, stream>>>((const unsigned int*)f16b, sortedg,
                                             startg, (float4*)d_out);
}

// Round 12
// 105.193 us; speedup vs baseline: 1.0881x; 1.0881x over previous
//
#include <hip/hip_runtime.h>
#include <hip/hip_bf16.h>
#include <math.h>

// FlexMaxPool: segment_max(features[in_idx], out_idx, num_segments=N_POINTS)
// R28 = R21 restored verbatim (best measured: 104.6us).
//  - R27 post-mortem: two-kernel L2-resident gather REGRESSED (+10us) despite
//    a true machine-wide phase barrier -> L2-residency is dead ON ITS OWN
//    TERMS: the gather's own streaming traffic (chunkd, sortedg, out writes)
//    evicts the 3.2MB "resident" half-table from the 4MB L2 (3.2MB + streams
//    > 4MB), plus 16MB sortedg round-trip and a duplicated prologue.
//  - Roofline: fills ~48us (fixed) + pool ~36us (117MB L2-miss line traffic
//    at ~3.3TB/s effective; R18 width / R25 MLP / R23 divergence / R22
//    granularity / R19+R24+R26+R27 residency all exhausted or falsified) +
//    binsort ~20us (scatter-free form; R20 restructure regressed).
//  - This is the structural floor of the binsort+gather algorithm.
//
// ws: feat16 6.4MB | chunkdata 256x6256 u32 (6.4MB) | pfxg 256x1024 u32 (1MB)

#define N_POINTS 50000
#define N_EDGES  1600000
#define CHANNELS 64
#define BIN_SHIFT 6
#define BIN_PTS   64
#define NBINS     782              // ceil(50000/64)
#define NBINS_PAD 1024
#define CAPL      2560             // per-bin list capacity (mean 2046, +11 sigma)
#define QCAP      2560
#define P1_GRID   256
#define P1_BLK    1024
#define ECHUNK    (N_EDGES / P1_GRID)               // 6250, exact
#define ECHUNK_PAD 6256                             // next multiple of 4
#define CVT_TOTAL (N_POINTS * CHANNELS / 4)         // 800000 float4
#define CVT_PER   ((CVT_TOTAL + P1_GRID - 1) / P1_GRID)   // 3125

__device__ __forceinline__ unsigned int encode_bf16(float x) {
    unsigned int u = __float_as_uint(x);
    unsigned int r = ((u >> 16) & 1u) + 0x7FFFu;
    unsigned int h = (u + r) >> 16;
    return (h & 0x8000u) ? (h ^ 0xFFFFu) : (h | 0x8000u);
}

__device__ __forceinline__ float decode_u16(unsigned int v) {
    if (v == 0u) return -INFINITY;
    unsigned int h = (v & 0x8000u) ? (v ^ 0x8000u) : (v ^ 0xFFFFu);
    return __uint_as_float(h << 16);
}

__device__ __forceinline__ unsigned int pk_max_u16(unsigned int a, unsigned int b) {
    unsigned int d;
    asm("v_pk_max_u16 %0, %1, %2" : "=v"(d) : "v"(a), "v"(b));
    return d;
}

// Counting sort of a 6250-edge chunk by 64-pt bin (dst>>6) into LDS, then a
// fully-coalesced contiguous dump (uint4) + per-chunk prefix table. Also this
// block's slice of the feature conversion.
// Entry: (bin:10 | dst_local:6 | src:16).
__global__ __launch_bounds__(P1_BLK) void binsort_cvt_kernel(
    const int2*   __restrict__ idx,
    const float4* __restrict__ feat4,
    uint2*        __restrict__ f16o,
    unsigned int* __restrict__ chunkd,
    unsigned int* __restrict__ pfxg)
{
    __shared__ unsigned int hist[NBINS_PAD];
    __shared__ unsigned int pfx[NBINS_PAD];
    __shared__ __align__(16) unsigned int staging[ECHUNK_PAD];   // 25 KB
    __shared__ unsigned int wsum[16];

    int tid  = threadIdx.x;
    int lane = tid & 63, w = tid >> 6;

    // ---- feature-convert slice (independent; overlaps the sort's LDS phases) ----
    {
        int cb = blockIdx.x * CVT_PER;
        #pragma unroll
        for (int k = 0; k < 4; ++k) {
            int i = cb + k * P1_BLK + tid;
            if (i < cb + CVT_PER && i < CVT_TOTAL) {
                float4 v = feat4[i];
                uint2 r;
                r.x = encode_bf16(v.x) | (encode_bf16(v.y) << 16);
                r.y = encode_bf16(v.z) | (encode_bf16(v.w) << 16);
                f16o[i] = r;
            }
        }
    }

    // ---- counting sort ----
    int base = blockIdx.x * ECHUNK;

    hist[tid] = 0u;
    __syncthreads();

    int2 e[7]; unsigned int slot[7];
    #pragma unroll
    for (int j = 0; j < 7; ++j) {
        int i = j * P1_BLK + tid;
        if (i < ECHUNK) {
            e[j] = idx[base + i];
            slot[j] = atomicAdd(&hist[(unsigned)e[j].x >> BIN_SHIFT], 1u);
        }
    }
    __syncthreads();

    // Exclusive prefix over 1024 bins, all 16 waves participating.
    {
        unsigned int a = hist[tid];
        unsigned int inc = a;
        #pragma unroll
        for (int d = 1; d < 64; d <<= 1) {
            unsigned int v = __shfl_up(inc, d, 64);
            if (lane >= d) inc += v;
        }
        if (lane == 63) wsum[w] = inc;
        __syncthreads();
        unsigned int woff = 0;
        #pragma unroll
        for (int k = 0; k < 16; ++k) if (k < w) woff += wsum[k];
        pfx[tid] = woff + inc - a;
    }
    __syncthreads();

    #pragma unroll
    for (int j = 0; j < 7; ++j) {
        int i = j * P1_BLK + tid;
        if (i < ECHUNK) {
            unsigned int dst = (unsigned)e[j].x, src = (unsigned)e[j].y;
            unsigned int bin = dst >> BIN_SHIFT;
            staging[pfx[bin] + slot[j]] =
                (bin << 22) | ((dst & (BIN_PTS - 1)) << 16) | src;
        }
    }
    if (tid < ECHUNK_PAD - ECHUNK) staging[ECHUNK + tid] = 0u;   // dump pad
    __syncthreads();

    // Fully-coalesced dump: 1564 uint4 + 1024-entry prefix table.
    {
        const uint4* st4 = (const uint4*)staging;
        uint4* cd4 = (uint4*)(chunkd + (size_t)blockIdx.x * ECHUNK_PAD);
        #pragma unroll
        for (int k = 0; k < 2; ++k) {
            int i = k * P1_BLK + tid;
            if (i < ECHUNK_PAD / 4) cd4[i] = st4[i];
        }
        pfxg[blockIdx.x * NBINS_PAD + tid] = pfx[tid];
    }
}

// One block per 64-pt bin; 512 threads. Prologue: concatenate the bin's 256
// chunk-segments (via pfxg) into LDS list[]. LDS sort by point
// (sorted[] = src*8, uint4-row units), then 8-lane-group uint4 gather
// (8 channels/lane) with 16 independent pk_max chains (4-deep unroll).
__global__ __launch_bounds__(512) void pool_kernel(
    const unsigned int* __restrict__ feat16,   // (N_POINTS, 32) u32: 2 encoded u16
    const unsigned int* __restrict__ chunkd,
    const unsigned int* __restrict__ pfxg,
    float4* __restrict__ out4)
{
    __shared__ unsigned int list[CAPL];        // 10 KB
    __shared__ unsigned int sorted[QCAP];      // 10 KB
    __shared__ unsigned int choff[P1_GRID];
    __shared__ unsigned int hist[64];
    __shared__ unsigned int start[65];
    __shared__ unsigned int cur[64];
    __shared__ unsigned int wsum4[4];
    __shared__ unsigned int Tsh;

    int tid = threadIdx.x;
    int bin = blockIdx.x;
    int lane = tid & 63, w = tid >> 6;

    if (tid < 64) hist[tid] = 0u;

    // Per-chunk segment bounds + exclusive scan of counts (4 waves).
    unsigned int cntc = 0, inc = 0;
    if (tid < P1_GRID) {
        unsigned int s = pfxg[tid * NBINS_PAD + bin];
        unsigned int e = pfxg[tid * NBINS_PAD + bin + 1];
        cntc = e - s;
        inc = cntc;
        #pragma unroll
        for (int d = 1; d < 64; d <<= 1) {
            unsigned int v = __shfl_up(inc, d, 64);
            if (lane >= d) inc += v;
        }
        if (lane == 63) wsum4[w] = inc;
    }
    __syncthreads();
    if (tid < P1_GRID) {
        unsigned int woff = 0;
        #pragma unroll
        for (int k = 0; k < 4; ++k) if (k < w) woff += wsum4[k];
        unsigned int off = woff + inc - cntc;
        choff[tid] = off;
        if (tid == P1_GRID - 1) Tsh = off + cntc;
    }
    __syncthreads();

    unsigned int T = Tsh; if (T > CAPL) T = CAPL;

    // Copy segments: 2 threads per chunk (interleaved halves).
    {
        int c = tid >> 1, h = tid & 1;
        unsigned int s = pfxg[c * NBINS_PAD + bin];
        unsigned int e = pfxg[c * NBINS_PAD + bin + 1];
        unsigned int n = e - s;
        unsigned int off = choff[c];
        unsigned int g0 = (unsigned)c * ECHUNK_PAD + s;
        for (unsigned int j = h; j < n; j += 2) {
            unsigned int v = chunkd[g0 + j];
            if (off + j < CAPL) list[off + j] = v;
        }
    }
    __syncthreads();

    // Histogram the bin's entries over 64 points.
    for (unsigned int t = tid; t < T; t += 512)
        atomicAdd(&hist[(list[t] >> 16) & 63], 1u);
    __syncthreads();

    // Scan 64 sub-bins with wave 0.
    if (tid < 64) {
        unsigned int h = hist[tid], inc2 = h;
        #pragma unroll
        for (int d = 1; d < 64; d <<= 1) {
            unsigned int v = __shfl_up(inc2, d, 64);
            if (tid >= d) inc2 += v;
        }
        start[tid] = inc2 - h; cur[tid] = inc2 - h;
        if (tid == 63) start[64] = inc2;
    }
    __syncthreads();

    for (unsigned int t = tid; t < T; t += 512) {
        unsigned int v = list[t];
        unsigned int slot = atomicAdd(&cur[(v >> 16) & 63], 1u);
        if (slot < QCAP) sorted[slot] = (v & 0xFFFFu) << 3;   // src * 8 uint4-rows
    }
    __syncthreads();

    // 8-lane group per point: lane ln holds channels 8*ln..8*ln+7 (one uint4).
    const uint4* frow = (const uint4*)feat16;
    int g = tid >> 3, ln = tid & 7;
    unsigned int s0 = start[g], s1 = start[g + 1];
    if (s1 > QCAP) s1 = QCAP;

    unsigned int A0=0,A1=0,A2=0,A3=0, B0=0,B1=0,B2=0,B3=0;
    unsigned int C0=0,C1=0,C2=0,C3=0, D0=0,D1=0,D2=0,D3=0;
    unsigned int i = s0;
    for (; i + 4 <= s1; i += 4) {
        unsigned int r0 = sorted[i+0], r1 = sorted[i+1];
        unsigned int r2 = sorted[i+2], r3 = sorted[i+3];
        uint4 u0 = frow[r0 + ln];
        uint4 u1 = frow[r1 + ln];
        uint4 u2 = frow[r2 + ln];
        uint4 u3 = frow[r3 + ln];
        A0 = pk_max_u16(A0, u0.x); A1 = pk_max_u16(A1, u0.y);
        A2 = pk_max_u16(A2, u0.z); A3 = pk_max_u16(A3, u0.w);
        B0 = pk_max_u16(B0, u1.x); B1 = pk_max_u16(B1, u1.y);
        B2 = pk_max_u16(B2, u1.z); B3 = pk_max_u16(B3, u1.w);
        C0 = pk_max_u16(C0, u2.x); C1 = pk_max_u16(C1, u2.y);
        C2 = pk_max_u16(C2, u2.z); C3 = pk_max_u16(C3, u2.w);
        D0 = pk_max_u16(D0, u3.x); D1 = pk_max_u16(D1, u3.y);
        D2 = pk_max_u16(D2, u3.z); D3 = pk_max_u16(D3, u3.w);
    }
    for (; i < s1; ++i) {
        uint4 u = frow[sorted[i] + ln];
        A0 = pk_max_u16(A0, u.x); A1 = pk_max_u16(A1, u.y);
        A2 = pk_max_u16(A2, u.z); A3 = pk_max_u16(A3, u.w);
    }
    A0 = pk_max_u16(pk_max_u16(A0, B0), pk_max_u16(C0, D0));
    A1 = pk_max_u16(pk_max_u16(A1, B1), pk_max_u16(C1, D1));
    A2 = pk_max_u16(pk_max_u16(A2, B2), pk_max_u16(C2, D2));
    A3 = pk_max_u16(pk_max_u16(A3, B3), pk_max_u16(C3, D3));

    int gp = bin * BIN_PTS + g;
    if (gp < N_POINTS) {
        float4 o0, o1;
        o0.x = decode_u16(A0 & 0xFFFFu); o0.y = decode_u16(A0 >> 16);
        o0.z = decode_u16(A1 & 0xFFFFu); o0.w = decode_u16(A1 >> 16);
        o1.x = decode_u16(A2 & 0xFFFFu); o1.y = decode_u16(A2 >> 16);
        o1.z = decode_u16(A3 & 0xFFFFu); o1.w = decode_u16(A3 >> 16);
        out4[(size_t)gp * 16 + ln * 2 + 0] = o0;
        out4[(size_t)gp * 16 + ln * 2 + 1] = o1;
    }
}

extern "C" void kernel_launch(void* const* d_in, const int* in_sizes, int n_in,
                              void* d_out, int out_size, void* d_ws, size_t ws_size,
                              hipStream_t stream) {
    const float4* feat4 = (const float4*)d_in[0];
    const int2*   idx   = (const int2*)d_in[1];

    size_t off_feat16 = 0;
    size_t off_chunk  = (size_t)N_POINTS * CHANNELS * 2;                 // 6.4 MB
    size_t off_pfxg   = off_chunk + (size_t)P1_GRID * ECHUNK_PAD * 4;    // +6.4 MB
    uint2*        f16o   = (uint2*)((char*)d_ws + off_feat16);
    unsigned int* feat16 = (unsigned int*)((char*)d_ws + off_feat16);
    unsigned int* chunkd = (unsigned int*)((char*)d_ws + off_chunk);
    unsigned int* pfxg   = (unsigned int*)((char*)d_ws + off_pfxg);

    binsort_cvt_kernel<<<P1_GRID, P1_BLK, 0, stream>>>(idx, feat4, f16o, chunkd, pfxg);
    pool_kernel<<<NBINS, 512, 0, stream>>>(feat16, chunkd, pfxg, (float4*)d_out);
}